// Round 4
// baseline (115.900 us; speedup 1.0000x reference)
//
#include <hip/hip_runtime.h>

#define NB    64
#define IN    512
#define OUT   512
#define NTOK  512       // B*T
#define K     2
#define NSEL  (NTOK*K)  // 1024
#define NTILE 8         // col tiles of 64
#define CW    64        // cols per tile
#define NHALF 2         // row halves of 256
#define RH    256       // rows per half
#define TCAP  16        // tokens per pass

// Pass 1: CSR lists of selection-indices per bank. Single block.
__global__ __launch_bounds__(1024) void build_lists(const int* __restrict__ sel,
                                                    int* __restrict__ counts,
                                                    int* __restrict__ offsets,
                                                    int* __restrict__ list) {
    __shared__ int lcnt[NB];
    __shared__ int loff[NB];
    const int t = threadIdx.x;
    if (t < NB) lcnt[t] = 0;
    __syncthreads();
    const int bank = sel[t];
    atomicAdd(&lcnt[bank], 1);
    __syncthreads();
    if (t == 0) {
        int run = 0;
        for (int b = 0; b < NB; ++b) { loff[b] = run; run += lcnt[b]; }
    }
    __syncthreads();
    if (t < NB) { counts[t] = lcnt[t]; offsets[t] = loff[t]; lcnt[t] = 0; }
    __syncthreads();
    const int pos = loff[bank] + atomicAdd(&lcnt[bank], 1);
    list[pos] = t;
}

// Pass 2: block = (bank, col-tile of 64, row-half of 256). 256 threads:
//   ct = t&15  -> float4 col within tile
//   rs = t>>4  -> row slice (16 slices; slice owns float4-row-blocks r4 = rs+16*it)
// Each thread: W fragment loaded ONCE, 16-token acc in registers.
// Reduce over slices: shfl_xor(16,32) in-wave, then 16KB LDS cross-wave.
__global__ __launch_bounds__(256, 4) void banked_gemv(
    const float* __restrict__ x,      // [NTOK][IN]
    const float* __restrict__ probs,  // [NSEL]
    const float* __restrict__ W,      // [NB][IN][OUT]
    const float* __restrict__ bias,   // [NB][OUT]
    const int* __restrict__ counts,
    const int* __restrict__ offsets,
    const int* __restrict__ list,
    float* __restrict__ ysel)         // [NSEL][NHALF][OUT]
{
    __shared__ __align__(16) float lds[TCAP * RH];   // 16 KB; xs and red alias
    float*  xs  = lds;                               // [16 tok][256 floats]
    float4* red = (float4*)lds;                      // [4 waves][16 tok][16 ct]
    __shared__ int   tok_s[TCAP];
    __shared__ float prob_s[TCAP];

    const int bank = blockIdx.x >> 4;
    const int tile = (blockIdx.x >> 1) & (NTILE - 1);
    const int half = blockIdx.x & 1;
    const int n    = counts[bank];
    if (n == 0) return;
    const int start = offsets[bank];
    const int col0  = tile * CW;
    const int row0  = half * RH;

    const int t  = threadIdx.x;
    const int ct = t & 15;
    const int rs = t >> 4;     // 0..15
    const int wv = t >> 6;     // 0..3

    const float* wbase = W + (size_t)bank * IN * OUT + (size_t)row0 * OUT + col0 + ct * 4;

    for (int c0 = 0; c0 < n; c0 += TCAP) {
        if (t < TCAP) {
            const int idx = c0 + t;
            const int e = (idx < n) ? list[start + idx] : -1;
            tok_s[t]  = (e >= 0) ? (e >> 1) : 0;
            prob_s[t] = (e >= 0) ? probs[e] : 0.0f;
        }
        __syncthreads();

        // stage xs pre-scaled: 16 tokens x 64 float4 = 1024; 4 per thread
        #pragma unroll
        for (int k2 = 0; k2 < 4; ++k2) {
            const int oid = t + k2 * 256;
            const int row = oid >> 6;       // token slot
            const int c4  = oid & 63;
            float4 v = *reinterpret_cast<const float4*>(x + (size_t)tok_s[row] * IN + row0 + c4 * 4);
            const float p = prob_s[row];
            v.x *= p; v.y *= p; v.z *= p; v.w *= p;
            reinterpret_cast<float4*>(xs + row * RH)[c4] = v;
        }
        __syncthreads();

        float4 acc[TCAP];
        #pragma unroll
        for (int j = 0; j < TCAP; ++j) acc[j] = make_float4(0.f, 0.f, 0.f, 0.f);

        #pragma unroll
        for (int it = 0; it < 4; ++it) {
            const int r4 = rs + 16 * it;          // float4-row block
            const float* wr = wbase + (size_t)(4 * r4) * OUT;
            const float4 w0 = *reinterpret_cast<const float4*>(wr);
            const float4 w1 = *reinterpret_cast<const float4*>(wr + OUT);
            const float4 w2 = *reinterpret_cast<const float4*>(wr + 2 * OUT);
            const float4 w3 = *reinterpret_cast<const float4*>(wr + 3 * OUT);
            #pragma unroll
            for (int j = 0; j < TCAP; ++j) {
                const float4 xv = *reinterpret_cast<const float4*>(xs + j * RH + 4 * r4);
                acc[j].x += xv.x * w0.x + xv.y * w1.x + xv.z * w2.x + xv.w * w3.x;
                acc[j].y += xv.x * w0.y + xv.y * w1.y + xv.z * w2.y + xv.w * w3.y;
                acc[j].z += xv.x * w0.z + xv.y * w1.z + xv.z * w2.z + xv.w * w3.z;
                acc[j].w += xv.x * w0.w + xv.y * w1.w + xv.z * w2.w + xv.w * w3.w;
            }
        }
        __syncthreads();   // xs fully consumed; lds reusable as red

        // in-wave reduce over lane bits 4,5 (rs low bits)
        #pragma unroll
        for (int j = 0; j < TCAP; ++j) {
            acc[j].x += __shfl_xor(acc[j].x, 16, 64);
            acc[j].y += __shfl_xor(acc[j].y, 16, 64);
            acc[j].z += __shfl_xor(acc[j].z, 16, 64);
            acc[j].w += __shfl_xor(acc[j].w, 16, 64);
            acc[j].x += __shfl_xor(acc[j].x, 32, 64);
            acc[j].y += __shfl_xor(acc[j].y, 32, 64);
            acc[j].z += __shfl_xor(acc[j].z, 32, 64);
            acc[j].w += __shfl_xor(acc[j].w, 32, 64);
        }
        if (((t >> 4) & 3) == 0) {
            #pragma unroll
            for (int j = 0; j < TCAP; ++j)
                red[(wv * TCAP + j) * 16 + ct] = acc[j];
        }
        __syncthreads();

        // final cross-wave reduce + store: 256 outputs, 1 per thread
        {
            const int s = t >> 4;     // token slot
            const int c = t & 15;     // float4 col
            if (c0 + s < n) {
                float4 a0 = red[(0 * TCAP + s) * 16 + c];
                float4 a1 = red[(1 * TCAP + s) * 16 + c];
                float4 a2 = red[(2 * TCAP + s) * 16 + c];
                float4 a3 = red[(3 * TCAP + s) * 16 + c];
                float4 sum;
                sum.x = (a0.x + a1.x) + (a2.x + a3.x);
                sum.y = (a0.y + a1.y) + (a2.y + a3.y);
                sum.z = (a0.z + a1.z) + (a2.z + a3.z);
                sum.w = (a0.w + a1.w) + (a2.w + a3.w);
                if (half == 0) {
                    const float p = prob_s[s];
                    const float4 bv = *reinterpret_cast<const float4*>(bias + bank * OUT + col0 + c * 4);
                    sum.x += p * bv.x; sum.y += p * bv.y; sum.z += p * bv.z; sum.w += p * bv.w;
                }
                const int e = list[start + c0 + s];
                *reinterpret_cast<float4*>(ysel + ((size_t)e * NHALF + half) * OUT + col0 + c * 4) = sum;
            }
        }
        __syncthreads();   // before restaging xs next pass
    }
}

// Pass 3: out[t] = sum over (k=2 selections) x (2 halves)
__global__ __launch_bounds__(256) void combine(const float* __restrict__ ysel,
                                               float* __restrict__ out) {
    const int i  = blockIdx.x * 256 + threadIdx.x;   // float4 index, 65536 total
    const int tk = i >> 7;          // token
    const int c  = i & 127;         // float4 col
    const float4* y4 = reinterpret_cast<const float4*>(ysel);
    // ysel layout: [e][half][OUT] -> float4 rows of 128 per (e,half)
    const size_t b0 = (size_t)(2 * tk) * 2 * 128;
    const float4 a = y4[b0 + c];
    const float4 b = y4[b0 + 128 + c];
    const float4 cc = y4[b0 + 256 + c];
    const float4 d = y4[b0 + 384 + c];
    float4 r;
    r.x = (a.x + b.x) + (cc.x + d.x);
    r.y = (a.y + b.y) + (cc.y + d.y);
    r.z = (a.z + b.z) + (cc.z + d.z);
    r.w = (a.w + b.w) + (cc.w + d.w);
    reinterpret_cast<float4*>(out)[i] = r;
}

extern "C" void kernel_launch(void* const* d_in, const int* in_sizes, int n_in,
                              void* d_out, int out_size, void* d_ws, size_t ws_size,
                              hipStream_t stream) {
    const float* x     = (const float*)d_in[0];
    const int*   sel   = (const int*)d_in[1];
    const float* probs = (const float*)d_in[2];
    const float* W     = (const float*)d_in[3];
    const float* bias  = (const float*)d_in[4];
    float* out = (float*)d_out;

    int* counts  = (int*)d_ws;        // 64
    int* offsets = counts + NB;       // 64
    int* list    = offsets + NB;      // 1024
    float* ysel  = (float*)((char*)d_ws + 4608);   // [NSEL][2][OUT] = 4 MB

    build_lists<<<1, NSEL, 0, stream>>>(sel, counts, offsets, list);
    banked_gemv<<<NB * NTILE * NHALF, 256, 0, stream>>>(x, probs, W, bias, counts, offsets, list, ysel);
    combine<<<(NTOK * OUT / 4) / 256, 256, 0, stream>>>(ysel, out);
}

// Round 5
// 30.548 us; speedup vs baseline: 3.7940x; 3.7940x over previous
//
#include <hip/hip_runtime.h>

#define NB    64
#define IN    512
#define OUT   512
#define NTOK  512       // B*T
#define K     2
#define NSEL  (NTOK*K)  // 1024
#define TCAP  32        // token slots per pass
#define XSTR  260       // xs float stride per slot (260%32=4 -> bank spread)

// Block = (bank, col-tile of 64, row-half of 256). 256 threads:
//   wave w = row slice (64 rows), lane: ct = l&15 (float4 col), g = l>>4
//   (token subgroup; W addr independent of g -> 4-way lane-dup, coalesced).
// Each thread: acc over 8 tokens (slots 4j+g) x 4 cols. W fragment read once.
// Cross-wave reduce via LDS (aliases xs). Per-selection stores, no atomics.
__global__ __launch_bounds__(256) void banked_gemv(
    const float* __restrict__ x,      // [NTOK][IN]
    const int*   __restrict__ sel,    // [NSEL]
    const float* __restrict__ probs,  // [NSEL]
    const float* __restrict__ W,      // [NB][IN][OUT]
    const float* __restrict__ bias,   // [NB][OUT]
    float* __restrict__ ysel)         // [NSEL][2][OUT]
{
    __shared__ __align__(16) float xs[TCAP * XSTR];   // 33.3 KB; red aliases
    __shared__ int   elist[NSEL];
    __shared__ int   lcnt;
    __shared__ int   tok_s[TCAP];
    __shared__ float prob_s[TCAP];

    const int bank = blockIdx.x >> 4;
    const int tile = (blockIdx.x >> 1) & 7;
    const int half = blockIdx.x & 1;
    const int t    = threadIdx.x;

    // build this bank's selection list (order-free; per-token math invariant)
    if (t == 0) lcnt = 0;
    __syncthreads();
    {
        const int4 s4 = reinterpret_cast<const int4*>(sel)[t];
        if (s4.x == bank) elist[atomicAdd(&lcnt, 1)] = 4 * t;
        if (s4.y == bank) elist[atomicAdd(&lcnt, 1)] = 4 * t + 1;
        if (s4.z == bank) elist[atomicAdd(&lcnt, 1)] = 4 * t + 2;
        if (s4.w == bank) elist[atomicAdd(&lcnt, 1)] = 4 * t + 3;
    }
    __syncthreads();
    const int n = lcnt;
    if (n == 0) return;

    const int l  = t & 63;
    const int w  = t >> 6;      // wave = row slice
    const int ct = l & 15;      // float4 col within 64-col tile
    const int g  = l >> 4;      // token subgroup 0..3
    const int col0 = tile * 64;
    const int row0 = half * 256 + w * 64;
    const float* wbase = W + (size_t)bank * (IN * OUT) + (size_t)row0 * OUT + col0 + ct * 4;

    for (int c0 = 0; c0 < n; c0 += TCAP) {
        if (t < TCAP) {
            const int idx = c0 + t;
            const int e = (idx < n) ? elist[idx] : -1;
            tok_s[t]  = (e >= 0) ? (e >> 1) : 0;
            prob_s[t] = (e >= 0) ? probs[e] : 0.0f;
        }
        __syncthreads();

        // stage xs pre-scaled: 32 slots x 64 float4 (this half's rows); 8/thread
        #pragma unroll
        for (int k2 = 0; k2 < 8; ++k2) {
            const int oid  = t + k2 * 256;
            const int slot = oid >> 6;
            const int c4   = oid & 63;
            float4 v = *reinterpret_cast<const float4*>(
                x + (size_t)tok_s[slot] * IN + half * 256 + c4 * 4);
            const float p = prob_s[slot];
            v.x *= p; v.y *= p; v.z *= p; v.w *= p;
            *reinterpret_cast<float4*>(xs + slot * XSTR + c4 * 4) = v;
        }
        __syncthreads();

        float4 acc[8];
        #pragma unroll
        for (int j = 0; j < 8; ++j) acc[j] = make_float4(0.f, 0.f, 0.f, 0.f);

        const float* xb = xs + w * 64;
        #pragma unroll 2
        for (int chunk = 0; chunk < 16; ++chunk) {
            const float* wr = wbase + (size_t)(chunk * 4) * OUT;
            const float4 w0 = *reinterpret_cast<const float4*>(wr);
            const float4 w1 = *reinterpret_cast<const float4*>(wr + OUT);
            const float4 w2 = *reinterpret_cast<const float4*>(wr + 2 * OUT);
            const float4 w3 = *reinterpret_cast<const float4*>(wr + 3 * OUT);
            #pragma unroll
            for (int j = 0; j < 8; ++j) {
                const float4 xv = *reinterpret_cast<const float4*>(
                    xb + (4 * j + g) * XSTR + chunk * 4);
                acc[j].x += xv.x * w0.x + xv.y * w1.x + xv.z * w2.x + xv.w * w3.x;
                acc[j].y += xv.x * w0.y + xv.y * w1.y + xv.z * w2.y + xv.w * w3.y;
                acc[j].z += xv.x * w0.z + xv.y * w1.z + xv.z * w2.z + xv.w * w3.z;
                acc[j].w += xv.x * w0.w + xv.y * w1.w + xv.z * w2.w + xv.w * w3.w;
            }
        }
        __syncthreads();   // xs consumed; reuse as red

        float4* red = reinterpret_cast<float4*>(xs);   // [w][slot][ct]
        #pragma unroll
        for (int j = 0; j < 8; ++j)
            red[w * (TCAP * 16) + (4 * j + g) * 16 + ct] = acc[j];
        __syncthreads();

        // final cross-wave reduce + store: 512 outputs, 2/thread
        #pragma unroll
        for (int k2 = 0; k2 < 2; ++k2) {
            const int oid  = t + k2 * 256;
            const int slot = oid >> 4;
            const int c    = oid & 15;
            if (c0 + slot < n) {
                const float4 a0 = red[0 * 512 + slot * 16 + c];
                const float4 a1 = red[1 * 512 + slot * 16 + c];
                const float4 a2 = red[2 * 512 + slot * 16 + c];
                const float4 a3 = red[3 * 512 + slot * 16 + c];
                float4 sum;
                sum.x = (a0.x + a1.x) + (a2.x + a3.x);
                sum.y = (a0.y + a1.y) + (a2.y + a3.y);
                sum.z = (a0.z + a1.z) + (a2.z + a3.z);
                sum.w = (a0.w + a1.w) + (a2.w + a3.w);
                if (half == 0) {
                    const float p = prob_s[slot];
                    const float4 bv = *reinterpret_cast<const float4*>(
                        bias + bank * OUT + col0 + c * 4);
                    sum.x += p * bv.x; sum.y += p * bv.y;
                    sum.z += p * bv.z; sum.w += p * bv.w;
                }
                const int e = elist[c0 + slot];
                *reinterpret_cast<float4*>(
                    ysel + ((size_t)e * 2 + half) * OUT + col0 + c * 4) = sum;
            }
        }
        __syncthreads();   // before restaging xs next pass
    }
}

// out[t] = sum over (k=2 selections) x (2 halves)
__global__ __launch_bounds__(256) void combine(const float* __restrict__ ysel,
                                               float* __restrict__ out) {
    const int i  = blockIdx.x * 256 + threadIdx.x;   // float4 index, 65536
    const int tk = i >> 7;
    const int c  = i & 127;
    const float4* y4 = reinterpret_cast<const float4*>(ysel);
    const size_t b0 = (size_t)(2 * tk) * 2 * 128;    // [e][half][128 f4]
    const float4 a  = y4[b0 + c];
    const float4 b  = y4[b0 + 128 + c];
    const float4 cc = y4[b0 + 256 + c];
    const float4 d  = y4[b0 + 384 + c];
    float4 r;
    r.x = (a.x + b.x) + (cc.x + d.x);
    r.y = (a.y + b.y) + (cc.y + d.y);
    r.z = (a.z + b.z) + (cc.z + d.z);
    r.w = (a.w + b.w) + (cc.w + d.w);
    reinterpret_cast<float4*>(out)[i] = r;
}

extern "C" void kernel_launch(void* const* d_in, const int* in_sizes, int n_in,
                              void* d_out, int out_size, void* d_ws, size_t ws_size,
                              hipStream_t stream) {
    const float* x     = (const float*)d_in[0];
    const int*   sel   = (const int*)d_in[1];
    const float* probs = (const float*)d_in[2];
    const float* W     = (const float*)d_in[3];
    const float* bias  = (const float*)d_in[4];
    float* out  = (float*)d_out;
    float* ysel = (float*)d_ws;     // [NSEL][2][OUT] = 4 MB

    banked_gemv<<<NB * 8 * 2, 256, 0, stream>>>(x, sel, probs, W, bias, ysel);
    combine<<<(NTOK * OUT / 4) / 256, 256, 0, stream>>>(ysel, out);
}